// Round 1
// baseline (341.805 us; speedup 1.0000x reference)
//
#include <hip/hip_runtime.h>
#include <hip/hip_bf16.h>
#include <cstdint>

// ---------------------------------------------------------------------------
// SingleHeadAttentionLayer: B=4, S=2048, D=KD=VD=1024, fp32 in/out.
// Pipeline (all bf16 MFMA GEMMs, m97-style 128x128/BK=32 tiles):
//   cast x,W* -> bf16
//   q,k,v = x @ W^T + b              (gemm_bt MODE 1, bf16 out)
//   Vt = v^T per batch               (LDS transpose)
//   P  = exp(|q@k^T / 32|) causal    (gemm_bt MODE 2, block-skip upper tri)
//   linv[row] = 1 / sum(P[row][0..row])
//   O  = (P @ V) * linv              (gemm_bt MODE 3, causal k-limit, A=P B=Vt)
//   out = O @ Wo^T + bo              (gemm_bt MODE 0, fp32 out)
// Workspace: ~126 MB (xb reused as O).
// ---------------------------------------------------------------------------

#define BM 128
#define BN 128
#define BK 32

typedef __attribute__((ext_vector_type(8))) __bf16 bf16x8;
typedef __attribute__((ext_vector_type(4))) __bf16 bf16x4;
typedef __attribute__((ext_vector_type(4))) float floatx4;

// async global->LDS, 16B per lane. LDS dest is wave-uniform base + lane*16;
// our per-thread lds offsets are exactly lane-linear (t*16 bytes), so this is
// the verified m97 pattern.
__device__ __forceinline__ void async_copy16(const __bf16* g, const __bf16* l) {
  __builtin_amdgcn_global_load_lds(
      (const __attribute__((address_space(1))) unsigned int*)(const void*)g,
      (__attribute__((address_space(3))) unsigned int*)(unsigned)(uintptr_t)(const void*)l,
      16, 0, 0);
}

// C[M][N] = A[M][K] @ B[N][K]^T  (both row-major, K contiguous)
// MODE 0: fp32 out, +bias
// MODE 1: bf16 out, +bias
// MODE 2: scores->P: p = (col<=row) ? exp(|acc/32|) : 0, bf16 out, batch-strided,
//         blocks with nb>mb skipped entirely (their P region is never read)
// MODE 3: PV: out = acc * linv[row], bf16 out, batch-strided, kSteps=(mb+1)*4
template <int MODE>
__global__ void __launch_bounds__(256, 2)
gemm_bt(const __bf16* __restrict__ A, const __bf16* __restrict__ B,
        const float* __restrict__ bias, void* __restrict__ Cout,
        const float* __restrict__ linv, int M, int N, int K,
        long sAb, long sBb, long sCb) {
  const int nb = blockIdx.x, mb = blockIdx.y, b = blockIdx.z;
  if (MODE == 2 && nb > mb) return;  // above causal diagonal: skip

  __shared__ __align__(16) __bf16 As[BM * BK];
  __shared__ __align__(16) __bf16 Bs[BN * BK];

  const __bf16* pA = A + (long)b * sAb;
  const __bf16* pB = B + (long)b * sBb;

  const int kSteps = (MODE == 3) ? (mb + 1) * (BM / BK) : (K / BK);

  const int t = threadIdx.x;
  const int lane = t & 63;
  const int wave = t >> 6;
  const int quad = lane >> 4;
  const int l16 = lane & 15;
  const int wm = wave >> 1;  // 2x2 wave grid, each wave does 64x64
  const int wn = wave & 1;

  // staging: thread t loads 8 bf16 (16B) at tile element t*8 (row t/4, col (t%4)*8),
  // twice per operand (rows 0..63 then 64..127)
  const __bf16* gA = pA + (long)(mb * BM + (t >> 2)) * K + ((t & 3) * 8);
  const __bf16* gB = pB + (long)(nb * BN + (t >> 2)) * K + ((t & 3) * 8);
  __bf16* lA = &As[t * 8];
  __bf16* lB = &Bs[t * 8];

  floatx4 acc[4][4] = {};

  for (int kk = 0; kk < kSteps; ++kk) {
    const long ko = (long)kk * BK;
    async_copy16(gA + ko, lA);
    async_copy16(gA + ko + (long)64 * K, lA + 2048);
    async_copy16(gB + ko, lB);
    async_copy16(gB + ko + (long)64 * K, lB + 2048);
    __syncthreads();  // drains vmcnt (global_load_lds) before reads

    bf16x8 af[4], bfr[4];
#pragma unroll
    for (int i = 0; i < 4; ++i) {
      af[i] = *(const bf16x8*)&As[(wm * 64 + i * 16 + l16) * BK + quad * 8];
      bfr[i] = *(const bf16x8*)&Bs[(wn * 64 + i * 16 + l16) * BK + quad * 8];
    }
#pragma unroll
    for (int i = 0; i < 4; ++i)
#pragma unroll
      for (int j = 0; j < 4; ++j)
        acc[i][j] =
            __builtin_amdgcn_mfma_f32_16x16x32_bf16(af[i], bfr[j], acc[i][j], 0, 0, 0);
    __syncthreads();  // all ds_reads done before next stage overwrites
  }

  // C/D layout (verified m89/m91): col = lane&15, row = quad*4 + reg
  const int rb = wm * 64 + quad * 4;
  const int cb = wn * 64 + l16;

  if constexpr (MODE == 0) {
    float* C = (float*)Cout;
#pragma unroll
    for (int j = 0; j < 4; ++j) {
      const int gc = nb * BN + cb + j * 16;
      const float bv = bias[gc];
#pragma unroll
      for (int i = 0; i < 4; ++i) {
        const int gr = mb * BM + rb + i * 16;
#pragma unroll
        for (int r = 0; r < 4; ++r) C[(long)(gr + r) * N + gc] = acc[i][j][r] + bv;
      }
    }
  } else if constexpr (MODE == 1) {
    __bf16* C = (__bf16*)Cout;
#pragma unroll
    for (int j = 0; j < 4; ++j) {
      const int gc = nb * BN + cb + j * 16;
      const float bv = bias[gc];
#pragma unroll
      for (int i = 0; i < 4; ++i) {
        const int gr = mb * BM + rb + i * 16;
#pragma unroll
        for (int r = 0; r < 4; ++r)
          C[(long)(gr + r) * N + gc] = (__bf16)(acc[i][j][r] + bv);
      }
    }
  } else if constexpr (MODE == 2) {
    __bf16* C = (__bf16*)Cout + (long)b * sCb;
    const float sc = 0.03125f;  // 1/sqrt(KD) = 1/32
#pragma unroll
    for (int i = 0; i < 4; ++i) {
#pragma unroll
      for (int r = 0; r < 4; ++r) {
        const int row = mb * BM + rb + i * 16 + r;
#pragma unroll
        for (int j = 0; j < 4; ++j) {
          const int col = nb * BN + cb + j * 16;
          // |s| in [0,~8] -> exp safe without max subtraction
          const float p = (col <= row) ? __expf(fabsf(acc[i][j][r] * sc)) : 0.f;
          C[(long)row * N + col] = (__bf16)p;
        }
      }
    }
  } else {  // MODE 3
    __bf16* C = (__bf16*)Cout + (long)b * sCb;
    const float* li = linv + (long)b * M;
#pragma unroll
    for (int i = 0; i < 4; ++i) {
#pragma unroll
      for (int r = 0; r < 4; ++r) {
        const int row = mb * BM + rb + i * 16 + r;
        const float s = li[row];
#pragma unroll
        for (int j = 0; j < 4; ++j) {
          const int col = nb * BN + cb + j * 16;
          C[(long)row * N + col] = (__bf16)(acc[i][j][r] * s);
        }
      }
    }
  }
}

__global__ void cast_f32_to_bf16(const float* __restrict__ in,
                                 __bf16* __restrict__ out, long n) {
  const long i = ((long)blockIdx.x * blockDim.x + threadIdx.x) * 4;
  if (i >= n) return;
  const float4 f = *(const float4*)(in + i);
  bf16x4 o;
  o[0] = (__bf16)f.x;
  o[1] = (__bf16)f.y;
  o[2] = (__bf16)f.z;
  o[3] = (__bf16)f.w;
  *(bf16x4*)(out + i) = o;
}

// out[b][c][r] = in[b][r][c];  in: [R][C] row-major per batch
__global__ void transpose_bf16(const __bf16* __restrict__ in,
                               __bf16* __restrict__ out, int R, int C) {
  __shared__ __bf16 tile[64][66];  // +2 pad: transposed reads hit all 32 banks
  const long boff = (long)blockIdx.z * R * C;
  const int r0 = blockIdx.y * 64, c0 = blockIdx.x * 64;
#pragma unroll
  for (int e = 0; e < 16; ++e) {
    const int idx = e * 256 + threadIdx.x;
    const int r = idx >> 6, c = idx & 63;
    tile[r][c] = in[boff + (long)(r0 + r) * C + (c0 + c)];
  }
  __syncthreads();
#pragma unroll
  for (int e = 0; e < 16; ++e) {
    const int idx = e * 256 + threadIdx.x;
    const int r = idx >> 6, c = idx & 63;
    out[boff + (long)(c0 + r) * R + (r0 + c)] = tile[c][r];
  }
}

// linv[b][row] = 1 / sum(P[b][row][0..row])  -- reads only the written
// (lower-triangular) region; everything beyond is 0xAA poison.
__global__ void rowsum_inv(const __bf16* __restrict__ P, float* __restrict__ linv,
                           int S) {
  const int row = blockIdx.x, b = blockIdx.y;
  const __bf16* pr = P + ((long)b * S + row) * (long)S;
  const int n = row + 1;
  float s = 0.f;
  for (int i = threadIdx.x; i < n; i += 256) s += (float)pr[i];
#pragma unroll
  for (int off = 32; off > 0; off >>= 1) s += __shfl_down(s, off, 64);
  __shared__ float wsum[4];
  if ((threadIdx.x & 63) == 0) wsum[threadIdx.x >> 6] = s;
  __syncthreads();
  if (threadIdx.x == 0)
    linv[(long)b * S + row] = 1.f / (wsum[0] + wsum[1] + wsum[2] + wsum[3]);
}

extern "C" void kernel_launch(void* const* d_in, const int* in_sizes, int n_in,
                              void* d_out, int out_size, void* d_ws, size_t ws_size,
                              hipStream_t stream) {
  const float* x = (const float*)d_in[0];
  const float* Wq = (const float*)d_in[1];
  const float* bq = (const float*)d_in[2];
  const float* Wk = (const float*)d_in[3];
  const float* bk = (const float*)d_in[4];
  const float* Wv = (const float*)d_in[5];
  const float* bv = (const float*)d_in[6];
  const float* Wo = (const float*)d_in[7];
  const float* bo = (const float*)d_in[8];
  float* out = (float*)d_out;

  constexpr int B = 4, S = 2048, D = 1024, KD = 1024, VD = 1024;
  constexpr long MB_ = 1024 * 1024;

  char* w = (char*)d_ws;
  __bf16* xb = (__bf16*)(w);             // 16 MB (reused as O later)
  __bf16* q = (__bf16*)(w + 16 * MB_);   // 16 MB
  __bf16* k = (__bf16*)(w + 32 * MB_);   // 16 MB
  __bf16* v = (__bf16*)(w + 48 * MB_);   // 16 MB
  __bf16* Vt = (__bf16*)(w + 64 * MB_);  // 16 MB
  __bf16* P = (__bf16*)(w + 80 * MB_);   // 32 MB
  __bf16* Wqb = (__bf16*)(w + 112 * MB_);
  __bf16* Wkb = (__bf16*)(w + 114 * MB_);
  __bf16* Wvb = (__bf16*)(w + 116 * MB_);
  __bf16* Wob = (__bf16*)(w + 118 * MB_);
  float* linv = (float*)(w + 120 * MB_);  // 32 KB
  __bf16* O = xb;  // xb dead after v projection

  // casts
  cast_f32_to_bf16<<<8192, 256, 0, stream>>>(x, xb, (long)B * S * D);
  cast_f32_to_bf16<<<1024, 256, 0, stream>>>(Wq, Wqb, (long)KD * D);
  cast_f32_to_bf16<<<1024, 256, 0, stream>>>(Wk, Wkb, (long)KD * D);
  cast_f32_to_bf16<<<1024, 256, 0, stream>>>(Wv, Wvb, (long)VD * D);
  cast_f32_to_bf16<<<1024, 256, 0, stream>>>(Wo, Wob, (long)D * VD);

  // projections: M = B*S = 8192 rows contiguous across batches
  const dim3 gp(KD / BN, (B * S) / BM, 1);
  gemm_bt<1><<<gp, 256, 0, stream>>>(xb, Wqb, bq, q, nullptr, B * S, KD, D, 0, 0, 0);
  gemm_bt<1><<<gp, 256, 0, stream>>>(xb, Wkb, bk, k, nullptr, B * S, KD, D, 0, 0, 0);
  gemm_bt<1><<<gp, 256, 0, stream>>>(xb, Wvb, bv, v, nullptr, B * S, VD, D, 0, 0, 0);

  // Vt[b][vd][s] = v[b][s][vd]
  transpose_bf16<<<dim3(VD / 64, S / 64, B), 256, 0, stream>>>(v, Vt, S, VD);

  // P = exp(|q k^T / 32|) with causal mask (lower-tri blocks only)
  gemm_bt<2><<<dim3(S / BN, S / BM, B), 256, 0, stream>>>(
      q, k, nullptr, P, nullptr, S, S, KD, (long)S * KD, (long)S * KD, (long)S * S);

  // row sums -> reciprocals
  rowsum_inv<<<dim3(S, B), 256, 0, stream>>>(P, linv, S);

  // O = (P @ V) * linv ; B operand = Vt[VD][S], causal k-limit per m-block
  gemm_bt<3><<<dim3(VD / BN, S / BM, B), 256, 0, stream>>>(
      P, Vt, nullptr, O, linv, S, VD, S, (long)S * S, (long)VD * S, (long)S * VD);

  // final: out = O @ Wo^T + bo (fp32)
  gemm_bt<0><<<dim3(D / BN, (B * S) / BM, 1), 256, 0, stream>>>(
      O, Wob, bo, out, nullptr, B * S, D, VD, 0, 0, 0);
}

// Round 2
// 305.231 us; speedup vs baseline: 1.1198x; 1.1198x over previous
//
#include <hip/hip_runtime.h>
#include <hip/hip_bf16.h>
#include <cstdint>

// ---------------------------------------------------------------------------
// SingleHeadAttentionLayer: B=4, S=2048, D=KD=VD=1024, fp32 in/out.
// Round 2: fusion round (every GEMM was latency-bound at ~2 blocks/CU).
//   cast x -> bf16; cast {Wq,Wk,Wv,Wo} -> bf16 (one dispatch)
//   q,k,Vt = x @ W^T + b   ONE dispatch, gridDim.z=3; V written transposed
//   P = exp(|q k^T|/32) causal, rowsums via in-epilogue atomics
//   O = (P @ V) / l        (ragged k, reads lsum)
//   out = O @ Wo^T + bo
// ---------------------------------------------------------------------------

#define BM 128
#define BN 128
#define BK 32

typedef __attribute__((ext_vector_type(8))) __bf16 bf16x8;
typedef __attribute__((ext_vector_type(4))) __bf16 bf16x4;
typedef __attribute__((ext_vector_type(4))) float floatx4;

struct Bias3 { const float* b[3]; };
struct Ptr4 { const float* p[4]; };

__device__ __forceinline__ void async_copy16(const __bf16* g, const __bf16* l) {
  __builtin_amdgcn_global_load_lds(
      (const __attribute__((address_space(1))) unsigned int*)(const void*)g,
      (__attribute__((address_space(3))) unsigned int*)(unsigned)(uintptr_t)(const void*)l,
      16, 0, 0);
}

// Shared 128x128/BK=32 bf16 MFMA main loop (m97 pattern).
// pA/pB already batch-offset; tiles selected by mb/nb. Accumulates 4x4 x floatx4.
__device__ __forceinline__ void gemm_core(const __bf16* __restrict__ pA,
                                          const __bf16* __restrict__ pB,
                                          int K, int kSteps, int mb, int nb,
                                          floatx4 (&acc)[4][4]) {
  __shared__ __align__(16) __bf16 As[BM * BK];
  __shared__ __align__(16) __bf16 Bs[BN * BK];

  const int t = threadIdx.x;
  const int lane = t & 63;
  const int wave = t >> 6;
  const int quad = lane >> 4;
  const int l16 = lane & 15;
  const int wm = wave >> 1;
  const int wn = wave & 1;

  const __bf16* gA = pA + (long)(mb * BM + (t >> 2)) * K + ((t & 3) * 8);
  const __bf16* gB = pB + (long)(nb * BN + (t >> 2)) * K + ((t & 3) * 8);
  __bf16* lA = &As[t * 8];
  __bf16* lB = &Bs[t * 8];

  for (int kk = 0; kk < kSteps; ++kk) {
    const long ko = (long)kk * BK;
    async_copy16(gA + ko, lA);
    async_copy16(gA + ko + (long)64 * K, lA + 2048);
    async_copy16(gB + ko, lB);
    async_copy16(gB + ko + (long)64 * K, lB + 2048);
    __syncthreads();

    bf16x8 af[4], bfr[4];
#pragma unroll
    for (int i = 0; i < 4; ++i) {
      af[i] = *(const bf16x8*)&As[(wm * 64 + i * 16 + l16) * BK + quad * 8];
      bfr[i] = *(const bf16x8*)&Bs[(wn * 64 + i * 16 + l16) * BK + quad * 8];
    }
#pragma unroll
    for (int i = 0; i < 4; ++i)
#pragma unroll
      for (int j = 0; j < 4; ++j)
        acc[i][j] =
            __builtin_amdgcn_mfma_f32_16x16x32_bf16(af[i], bfr[j], acc[i][j], 0, 0, 0);
    __syncthreads();
  }
}

// ---------------- fused QKV projection (z = 0:q, 1:k, 2:v-transposed) -------
__global__ void __launch_bounds__(256, 2)
gemm_qkv(const __bf16* __restrict__ xb, const __bf16* __restrict__ Wqkv,
         Bias3 bias, __bf16* __restrict__ qk, __bf16* __restrict__ Vt,
         int S, int D, int KD, int B) {
  const int nb = blockIdx.x, mb = blockIdx.y, z = blockIdx.z;
  floatx4 acc[4][4] = {};
  gemm_core(xb, Wqkv + (long)z * KD * D, D, D / BK, mb, nb, acc);

  const int t = threadIdx.x;
  const int lane = t & 63, wave = t >> 6;
  const int rb = (wave >> 1) * 64 + (lane >> 4) * 4;
  const int cb = (wave & 1) * 64 + (lane & 15);
  const float* bz = bias.b[z];

  if (z < 2) {
    __bf16* C = qk + (long)z * B * S * KD;
#pragma unroll
    for (int j = 0; j < 4; ++j) {
      const int gc = nb * BN + cb + j * 16;
      const float bv = bz[gc];
#pragma unroll
      for (int i = 0; i < 4; ++i) {
        const int gr = mb * BM + rb + i * 16;
#pragma unroll
        for (int r = 0; r < 4; ++r)
          C[(long)(gr + r) * KD + gc] = (__bf16)(acc[i][j][r] + bv);
      }
    }
  } else {
    // Vt[b][vd][s] = v[b][s][vd]; BM=128 rows lie in one batch (S%BM==0)
    const int bb = (mb * BM) / S;
    const int s0 = mb * BM - bb * S;
#pragma unroll
    for (int j = 0; j < 4; ++j) {
      const int gc = nb * BN + cb + j * 16;  // vd
      const float bv = bz[gc];
#pragma unroll
      for (int i = 0; i < 4; ++i) {
        const int sr = s0 + rb + i * 16;
        bf16x4 o;
#pragma unroll
        for (int r = 0; r < 4; ++r) o[r] = (__bf16)(acc[i][j][r] + bv);
        *(bf16x4*)&Vt[((long)bb * KD + gc) * S + sr] = o;
      }
    }
  }
}

// ---------------- scores: P = exp(|qk^T|/32) causal, + atomic rowsums -------
__global__ void __launch_bounds__(256, 2)
gemm_scores(const __bf16* __restrict__ q, const __bf16* __restrict__ k,
            __bf16* __restrict__ P, float* __restrict__ lsum, int S, int KD) {
  const int nb = blockIdx.x, mb = blockIdx.y, b = blockIdx.z;
  if (nb > mb) return;  // above causal diagonal: never read downstream
  floatx4 acc[4][4] = {};
  gemm_core(q + (long)b * S * KD, k + (long)b * S * KD, KD, KD / BK, mb, nb, acc);

  const int t = threadIdx.x;
  const int lane = t & 63, wave = t >> 6;
  const int l16 = lane & 15;
  const int rb = (wave >> 1) * 64 + ((lane >> 4)) * 4;
  const int cb = (wave & 1) * 64 + l16;
  __bf16* C = P + (long)b * S * S;
  float* lrow = lsum + (long)b * S;
  const float sc = 0.03125f;  // 1/sqrt(1024)

#pragma unroll
  for (int i = 0; i < 4; ++i) {
#pragma unroll
    for (int r = 0; r < 4; ++r) {
      const int row = mb * BM + rb + i * 16 + r;
      float psum = 0.f;
#pragma unroll
      for (int j = 0; j < 4; ++j) {
        const int col = nb * BN + cb + j * 16;
        const float p = (col <= row) ? __expf(fabsf(acc[i][j][r] * sc)) : 0.f;
        psum += p;
        C[(long)row * S + col] = (__bf16)p;
      }
      // 16 lanes of this quad share `row` (row independent of l16): reduce
      psum += __shfl_xor(psum, 1, 64);
      psum += __shfl_xor(psum, 2, 64);
      psum += __shfl_xor(psum, 4, 64);
      psum += __shfl_xor(psum, 8, 64);
      if (l16 == 0) atomicAdd(&lrow[row], psum);
    }
  }
}

// ---------------- PV: O = (P @ V) / l, ragged causal k ----------------------
__global__ void __launch_bounds__(256, 2)
gemm_pv(const __bf16* __restrict__ P, const __bf16* __restrict__ Vt,
        const float* __restrict__ lsum, __bf16* __restrict__ O, int S, int VD) {
  const int nb = blockIdx.x, mb = blockIdx.y, b = blockIdx.z;
  floatx4 acc[4][4] = {};
  gemm_core(P + (long)b * S * S, Vt + (long)b * VD * S, S, (mb + 1) * (BM / BK),
            mb, nb, acc);

  const int t = threadIdx.x;
  const int lane = t & 63, wave = t >> 6;
  const int rb = (wave >> 1) * 64 + (lane >> 4) * 4;
  const int cb = (wave & 1) * 64 + (lane & 15);
  const float* lrow = lsum + (long)b * S;

#pragma unroll
  for (int i = 0; i < 4; ++i) {
#pragma unroll
    for (int r = 0; r < 4; ++r) {
      const int row = mb * BM + rb + i * 16 + r;
      const float inv = 1.f / lrow[row];
#pragma unroll
      for (int j = 0; j < 4; ++j) {
        const int col = nb * BN + cb + j * 16;
        O[((long)b * S + row) * VD + col] = (__bf16)(acc[i][j][r] * inv);
      }
    }
  }
}

// ---------------- final projection: out = O @ Wo^T + bo (fp32) --------------
__global__ void __launch_bounds__(256, 2)
gemm_out(const __bf16* __restrict__ O, const __bf16* __restrict__ Wob,
         const float* __restrict__ bo, float* __restrict__ out, int M, int N,
         int K) {
  const int nb = blockIdx.x, mb = blockIdx.y;
  floatx4 acc[4][4] = {};
  gemm_core(O, Wob, K, K / BK, mb, nb, acc);

  const int t = threadIdx.x;
  const int lane = t & 63, wave = t >> 6;
  const int rb = (wave >> 1) * 64 + (lane >> 4) * 4;
  const int cb = (wave & 1) * 64 + (lane & 15);

#pragma unroll
  for (int j = 0; j < 4; ++j) {
    const int gc = nb * BN + cb + j * 16;
    const float bv = bo[gc];
#pragma unroll
    for (int i = 0; i < 4; ++i) {
      const int gr = mb * BM + rb + i * 16;
#pragma unroll
      for (int r = 0; r < 4; ++r) out[(long)(gr + r) * N + gc] = acc[i][j][r] + bv;
    }
  }
}

// ---------------- casts -----------------------------------------------------
__global__ void cast_f32_to_bf16(const float* __restrict__ in,
                                 __bf16* __restrict__ out, long n) {
  const long i = ((long)blockIdx.x * blockDim.x + threadIdx.x) * 4;
  if (i >= n) return;
  const float4 f = *(const float4*)(in + i);
  bf16x4 o;
  o[0] = (__bf16)f.x; o[1] = (__bf16)f.y; o[2] = (__bf16)f.z; o[3] = (__bf16)f.w;
  *(bf16x4*)(out + i) = o;
}

// 4 weight matrices (1M elems each) -> contiguous bf16 dst, one dispatch
__global__ void cast4_f32_to_bf16(Ptr4 in, __bf16* __restrict__ out) {
  const int slot = blockIdx.x * 256 + threadIdx.x;   // float4 slot, 4*2^18 total
  const int which = slot >> 18;
  const long e = (long)(slot & 0x3ffff) * 4;
  const float4 f = *(const float4*)(in.p[which] + e);
  bf16x4 o;
  o[0] = (__bf16)f.x; o[1] = (__bf16)f.y; o[2] = (__bf16)f.z; o[3] = (__bf16)f.w;
  *(bf16x4*)(out + ((long)which << 20) + e) = o;
}

extern "C" void kernel_launch(void* const* d_in, const int* in_sizes, int n_in,
                              void* d_out, int out_size, void* d_ws, size_t ws_size,
                              hipStream_t stream) {
  const float* x = (const float*)d_in[0];
  const float* Wq = (const float*)d_in[1];
  const float* bq = (const float*)d_in[2];
  const float* Wk = (const float*)d_in[3];
  const float* bk = (const float*)d_in[4];
  const float* Wv = (const float*)d_in[5];
  const float* bv = (const float*)d_in[6];
  const float* Wo = (const float*)d_in[7];
  const float* bo = (const float*)d_in[8];
  float* out = (float*)d_out;

  constexpr int B = 4, S = 2048, D = 1024, KD = 1024, VD = 1024;
  constexpr long MB_ = 1024 * 1024;

  char* w = (char*)d_ws;
  __bf16* xb = (__bf16*)(w);              // 16 MB (reused as O later)
  __bf16* qk = (__bf16*)(w + 16 * MB_);   // 32 MB: q then k
  __bf16* Vt = (__bf16*)(w + 48 * MB_);   // 16 MB
  __bf16* P  = (__bf16*)(w + 64 * MB_);   // 32 MB
  __bf16* Wb = (__bf16*)(w + 96 * MB_);   // 8 MB: Wq,Wk,Wv,Wo bf16 contiguous
  float* lsum = (float*)(w + 104 * MB_);  // 32 KB
  __bf16* O = xb;  // xb dead after qkv

  hipMemsetAsync(lsum, 0, (long)B * S * sizeof(float), stream);

  cast_f32_to_bf16<<<8192, 256, 0, stream>>>(x, xb, (long)B * S * D);
  Ptr4 wp{{Wq, Wk, Wv, Wo}};
  cast4_f32_to_bf16<<<4096, 256, 0, stream>>>(wp, Wb);

  Bias3 b3{{bq, bk, bv}};
  gemm_qkv<<<dim3(KD / BN, (B * S) / BM, 3), 256, 0, stream>>>(
      xb, Wb, b3, qk, Vt, S, D, KD, B);

  gemm_scores<<<dim3(S / BN, S / BM, B), 256, 0, stream>>>(
      qk, qk + (long)B * S * KD, P, lsum, S, KD);

  gemm_pv<<<dim3(VD / BN, S / BM, B), 256, 0, stream>>>(P, Vt, lsum, O, S, VD);

  gemm_out<<<dim3(D / BN, (B * S) / BM, 1), 256, 0, stream>>>(
      O, Wb + 3l * D * VD, bo, out, B * S, D, VD);
}

// Round 3
// 284.624 us; speedup vs baseline: 1.2009x; 1.0724x over previous
//
#include <hip/hip_runtime.h>
#include <hip/hip_bf16.h>
#include <cstdint>

// ---------------------------------------------------------------------------
// SingleHeadAttentionLayer: B=4, S=2048, D=KD=VD=1024, fp32 in/out.
// Round 3: BK=64 via two 32-wide panels per barrier pair (halves the
// vmcnt(0)-drain barrier count that dominates the K-loop), one prep dispatch.
//   prep: cast x->bf16, cast {Wq,Wk,Wv,Wo}->bf16, zero lsum (one dispatch)
//   q,k,Vt = x @ W^T + b   (one dispatch, z=3; V written transposed)
//   P = exp(|q k^T|/32) causal, rowsums via in-epilogue atomics
//   O = (P @ V) / l        (ragged causal k)
//   out = O @ Wo^T + bo
// ---------------------------------------------------------------------------

#define BM 128
#define BN 128

typedef __attribute__((ext_vector_type(8))) __bf16 bf16x8;
typedef __attribute__((ext_vector_type(4))) __bf16 bf16x4;
typedef __attribute__((ext_vector_type(4))) float floatx4;

struct Bias3 { const float* b[3]; };
struct Ptr4 { const float* p[4]; };

__device__ __forceinline__ void async_copy16(const __bf16* g, const __bf16* l) {
  __builtin_amdgcn_global_load_lds(
      (const __attribute__((address_space(1))) unsigned int*)(const void*)g,
      (__attribute__((address_space(3))) unsigned int*)(unsigned)(uintptr_t)(const void*)l,
      16, 0, 0);
}

// 128x128 tile, K consumed 64 at a time as two 32-panels in separate 8 KB
// LDS buffers (keeps the verified lane-linear global_load_lds layout and the
// free 2-way bank pattern of BK=32). kSteps64 = K/64 iterations.
__device__ __forceinline__ void gemm_core(const __bf16* __restrict__ pA,
                                          const __bf16* __restrict__ pB,
                                          int K, int kSteps64, int mb, int nb,
                                          floatx4 (&acc)[4][4]) {
  __shared__ __align__(16) __bf16 As0[BM * 32];
  __shared__ __align__(16) __bf16 As1[BM * 32];
  __shared__ __align__(16) __bf16 Bs0[BN * 32];
  __shared__ __align__(16) __bf16 Bs1[BN * 32];

  const int t = threadIdx.x;
  const int lane = t & 63;
  const int wave = t >> 6;
  const int quad = lane >> 4;
  const int l16 = lane & 15;
  const int wm = wave >> 1;
  const int wn = wave & 1;

  const __bf16* gA = pA + (long)(mb * BM + (t >> 2)) * K + ((t & 3) * 8);
  const __bf16* gB = pB + (long)(nb * BN + (t >> 2)) * K + ((t & 3) * 8);
  const long rowHalf = (long)64 * K;  // +64 rows
  __bf16* lA0 = &As0[t * 8];
  __bf16* lA1 = &As1[t * 8];
  __bf16* lB0 = &Bs0[t * 8];
  __bf16* lB1 = &Bs1[t * 8];

  for (int kk = 0; kk < kSteps64; ++kk) {
    const long ko = (long)kk * 64;
    async_copy16(gA + ko, lA0);
    async_copy16(gA + ko + rowHalf, lA0 + 2048);
    async_copy16(gA + ko + 32, lA1);
    async_copy16(gA + ko + 32 + rowHalf, lA1 + 2048);
    async_copy16(gB + ko, lB0);
    async_copy16(gB + ko + rowHalf, lB0 + 2048);
    async_copy16(gB + ko + 32, lB1);
    async_copy16(gB + ko + 32 + rowHalf, lB1 + 2048);
    __syncthreads();  // drains vmcnt before LDS reads

#pragma unroll
    for (int p = 0; p < 2; ++p) {
      const __bf16* As = p ? As1 : As0;
      const __bf16* Bs = p ? Bs1 : Bs0;
      bf16x8 af[4], bfr[4];
#pragma unroll
      for (int i = 0; i < 4; ++i) {
        af[i] = *(const bf16x8*)&As[(wm * 64 + i * 16 + l16) * 32 + quad * 8];
        bfr[i] = *(const bf16x8*)&Bs[(wn * 64 + i * 16 + l16) * 32 + quad * 8];
      }
#pragma unroll
      for (int i = 0; i < 4; ++i)
#pragma unroll
        for (int j = 0; j < 4; ++j)
          acc[i][j] = __builtin_amdgcn_mfma_f32_16x16x32_bf16(af[i], bfr[j],
                                                              acc[i][j], 0, 0, 0);
    }
    __syncthreads();  // ds_reads done before next stage overwrites
  }
}

// ---------------- fused QKV projection (z = 0:q, 1:k, 2:v-transposed) -------
__global__ void __launch_bounds__(256, 2)
gemm_qkv(const __bf16* __restrict__ xb, const __bf16* __restrict__ Wqkv,
         Bias3 bias, __bf16* __restrict__ qk, __bf16* __restrict__ Vt,
         int S, int D, int KD, int B) {
  const int nb = blockIdx.x, mb = blockIdx.y, z = blockIdx.z;
  floatx4 acc[4][4] = {};
  gemm_core(xb, Wqkv + (long)z * KD * D, D, D / 64, mb, nb, acc);

  const int t = threadIdx.x;
  const int lane = t & 63, wave = t >> 6;
  const int rb = (wave >> 1) * 64 + (lane >> 4) * 4;
  const int cb = (wave & 1) * 64 + (lane & 15);
  const float* bz = bias.b[z];

  if (z < 2) {
    __bf16* C = qk + (long)z * B * S * KD;
#pragma unroll
    for (int j = 0; j < 4; ++j) {
      const int gc = nb * BN + cb + j * 16;
      const float bv = bz[gc];
#pragma unroll
      for (int i = 0; i < 4; ++i) {
        const int gr = mb * BM + rb + i * 16;
#pragma unroll
        for (int r = 0; r < 4; ++r)
          C[(long)(gr + r) * KD + gc] = (__bf16)(acc[i][j][r] + bv);
      }
    }
  } else {
    // Vt[b][vd][s] = v[b][s][vd]; BM=128 rows lie in one batch (S%BM==0)
    const int bb = (mb * BM) / S;
    const int s0 = mb * BM - bb * S;
#pragma unroll
    for (int j = 0; j < 4; ++j) {
      const int gc = nb * BN + cb + j * 16;  // vd
      const float bv = bz[gc];
#pragma unroll
      for (int i = 0; i < 4; ++i) {
        const int sr = s0 + rb + i * 16;
        bf16x4 o;
#pragma unroll
        for (int r = 0; r < 4; ++r) o[r] = (__bf16)(acc[i][j][r] + bv);
        *(bf16x4*)&Vt[((long)bb * KD + gc) * S + sr] = o;
      }
    }
  }
}

// ---------------- scores: P = exp(|qk^T|/32) causal, + atomic rowsums -------
__global__ void __launch_bounds__(256, 2)
gemm_scores(const __bf16* __restrict__ q, const __bf16* __restrict__ k,
            __bf16* __restrict__ P, float* __restrict__ lsum, int S, int KD) {
  const int nb = blockIdx.x, mb = blockIdx.y, b = blockIdx.z;
  if (nb > mb) return;  // above causal diagonal: never read downstream
  floatx4 acc[4][4] = {};
  gemm_core(q + (long)b * S * KD, k + (long)b * S * KD, KD, KD / 64, mb, nb, acc);

  const int t = threadIdx.x;
  const int lane = t & 63, wave = t >> 6;
  const int l16 = lane & 15;
  const int rb = (wave >> 1) * 64 + (lane >> 4) * 4;
  const int cb = (wave & 1) * 64 + l16;
  __bf16* C = P + (long)b * S * S;
  float* lrow = lsum + (long)b * S;
  const float sc = 0.03125f;  // 1/sqrt(1024)

#pragma unroll
  for (int i = 0; i < 4; ++i) {
#pragma unroll
    for (int r = 0; r < 4; ++r) {
      const int row = mb * BM + rb + i * 16 + r;
      float psum = 0.f;
#pragma unroll
      for (int j = 0; j < 4; ++j) {
        const int col = nb * BN + cb + j * 16;
        const float p = (col <= row) ? __expf(fabsf(acc[i][j][r] * sc)) : 0.f;
        psum += p;
        C[(long)row * S + col] = (__bf16)p;
      }
      // 16 lanes of this quad share `row`: butterfly then one atomic
      psum += __shfl_xor(psum, 1, 64);
      psum += __shfl_xor(psum, 2, 64);
      psum += __shfl_xor(psum, 4, 64);
      psum += __shfl_xor(psum, 8, 64);
      if (l16 == 0) atomicAdd(&lrow[row], psum);
    }
  }
}

// ---------------- PV: O = (P @ V) / l, ragged causal k ----------------------
__global__ void __launch_bounds__(256, 2)
gemm_pv(const __bf16* __restrict__ P, const __bf16* __restrict__ Vt,
        const float* __restrict__ lsum, __bf16* __restrict__ O, int S, int VD) {
  const int nb = blockIdx.x, mb = blockIdx.y, b = blockIdx.z;
  floatx4 acc[4][4] = {};
  gemm_core(P + (long)b * S * S, Vt + (long)b * VD * S, S, (mb + 1) * 2, mb, nb,
            acc);

  const int t = threadIdx.x;
  const int lane = t & 63, wave = t >> 6;
  const int rb = (wave >> 1) * 64 + (lane >> 4) * 4;
  const int cb = (wave & 1) * 64 + (lane & 15);
  const float* lrow = lsum + (long)b * S;

#pragma unroll
  for (int i = 0; i < 4; ++i) {
#pragma unroll
    for (int r = 0; r < 4; ++r) {
      const int row = mb * BM + rb + i * 16 + r;
      const float inv = 1.f / lrow[row];
#pragma unroll
      for (int j = 0; j < 4; ++j) {
        const int col = nb * BN + cb + j * 16;
        O[((long)b * S + row) * VD + col] = (__bf16)(acc[i][j][r] * inv);
      }
    }
  }
}

// ---------------- final projection: out = O @ Wo^T + bo (fp32) --------------
__global__ void __launch_bounds__(256, 2)
gemm_out(const __bf16* __restrict__ O, const __bf16* __restrict__ Wob,
         const float* __restrict__ bo, float* __restrict__ out, int M, int N,
         int K) {
  const int nb = blockIdx.x, mb = blockIdx.y;
  floatx4 acc[4][4] = {};
  gemm_core(O, Wob, K, K / 64, mb, nb, acc);

  const int t = threadIdx.x;
  const int lane = t & 63, wave = t >> 6;
  const int rb = (wave >> 1) * 64 + (lane >> 4) * 4;
  const int cb = (wave & 1) * 64 + (lane & 15);

#pragma unroll
  for (int j = 0; j < 4; ++j) {
    const int gc = nb * BN + cb + j * 16;
    const float bv = bo[gc];
#pragma unroll
    for (int i = 0; i < 4; ++i) {
      const int gr = mb * BM + rb + i * 16;
#pragma unroll
      for (int r = 0; r < 4; ++r) out[(long)(gr + r) * N + gc] = acc[i][j][r] + bv;
    }
  }
}

// ---------------- prep: cast x, cast 4 weights, zero lsum (one dispatch) ----
__global__ void prep(const float* __restrict__ x, Ptr4 wp,
                     __bf16* __restrict__ xb, __bf16* __restrict__ Wb,
                     float* __restrict__ lsum) {
  const int bid = blockIdx.x;
  const int t = threadIdx.x;
  if (bid < 8192) {  // x: 8M elems = 2M float4 slots
    const long i = ((long)bid * 256 + t) * 4;
    const float4 f = *(const float4*)(x + i);
    bf16x4 o;
    o[0] = (__bf16)f.x; o[1] = (__bf16)f.y; o[2] = (__bf16)f.z; o[3] = (__bf16)f.w;
    *(bf16x4*)(xb + i) = o;
  } else if (bid < 12288) {  // weights: 4 x 1M elems
    const int slot = (bid - 8192) * 256 + t;
    const int which = slot >> 18;
    const long e = (long)(slot & 0x3ffff) * 4;
    const float4 f = *(const float4*)(wp.p[which] + e);
    bf16x4 o;
    o[0] = (__bf16)f.x; o[1] = (__bf16)f.y; o[2] = (__bf16)f.z; o[3] = (__bf16)f.w;
    *(bf16x4*)(Wb + ((long)which << 20) + e) = o;
  } else {  // zero lsum: 8192 floats = 2048 float4
#pragma unroll
    for (int e = 0; e < 8; ++e)
      *(float4*)(lsum + (e * 256 + t) * 4) = float4{0.f, 0.f, 0.f, 0.f};
  }
}

extern "C" void kernel_launch(void* const* d_in, const int* in_sizes, int n_in,
                              void* d_out, int out_size, void* d_ws, size_t ws_size,
                              hipStream_t stream) {
  const float* x = (const float*)d_in[0];
  const float* Wq = (const float*)d_in[1];
  const float* bq = (const float*)d_in[2];
  const float* Wk = (const float*)d_in[3];
  const float* bk = (const float*)d_in[4];
  const float* Wv = (const float*)d_in[5];
  const float* bv = (const float*)d_in[6];
  const float* Wo = (const float*)d_in[7];
  const float* bo = (const float*)d_in[8];
  float* out = (float*)d_out;

  constexpr int B = 4, S = 2048, D = 1024, KD = 1024, VD = 1024;
  constexpr long MB_ = 1024 * 1024;

  char* w = (char*)d_ws;
  __bf16* xb = (__bf16*)(w);              // 16 MB (reused as O later)
  __bf16* qk = (__bf16*)(w + 16 * MB_);   // 32 MB: q then k
  __bf16* Vt = (__bf16*)(w + 48 * MB_);   // 16 MB
  __bf16* P  = (__bf16*)(w + 64 * MB_);   // 32 MB
  __bf16* Wb = (__bf16*)(w + 96 * MB_);   // 8 MB: Wq,Wk,Wv,Wo bf16 contiguous
  float* lsum = (float*)(w + 104 * MB_);  // 32 KB
  __bf16* O = xb;  // xb dead after qkv

  Ptr4 wp{{Wq, Wk, Wv, Wo}};
  prep<<<12289, 256, 0, stream>>>(x, wp, xb, Wb, lsum);

  Bias3 b3{{bq, bk, bv}};
  gemm_qkv<<<dim3(KD / BN, (B * S) / BM, 3), 256, 0, stream>>>(
      xb, Wb, b3, qk, Vt, S, D, KD, B);

  gemm_scores<<<dim3(S / BN, S / BM, B), 256, 0, stream>>>(
      qk, qk + (long)B * S * KD, P, lsum, S, KD);

  gemm_pv<<<dim3(VD / BN, S / BM, B), 256, 0, stream>>>(P, Vt, lsum, O, S, VD);

  gemm_out<<<dim3(D / BN, (B * S) / BM, 1), 256, 0, stream>>>(
      O, Wb + 3l * D * VD, bo, out, B * S, D, VD);
}

// Round 4
// 264.441 us; speedup vs baseline: 1.2926x; 1.0763x over previous
//
#include <hip/hip_runtime.h>
#include <hip/hip_bf16.h>
#include <cstdint>

// ---------------------------------------------------------------------------
// SingleHeadAttentionLayer: B=4, S=2048, D=KD=VD=1024, fp32 in/out.
// Round 4: XCD-locality swizzle. All GEMM grids flattened to 1-D; block id
// remapped so blocks sharing an A-panel satisfy id%8 == same XCD (round-robin
// heuristic). Per XCD: 8 A-panels (2 MB) stay L2-resident; B streams (L3
// serves cross-XCD re-reads). Triangular/ragged kernels use the balanced
// mb in {x, 15-x} pairing so per-XCD work is uniform.
// ---------------------------------------------------------------------------

#define BM 128
#define BN 128

typedef __attribute__((ext_vector_type(8))) __bf16 bf16x8;
typedef __attribute__((ext_vector_type(4))) __bf16 bf16x4;
typedef __attribute__((ext_vector_type(4))) float floatx4;

struct Bias3 { const float* b[3]; };
struct Ptr4 { const float* p[4]; };

__device__ __forceinline__ void async_copy16(const __bf16* g, const __bf16* l) {
  __builtin_amdgcn_global_load_lds(
      (const __attribute__((address_space(1))) unsigned int*)(const void*)g,
      (__attribute__((address_space(3))) unsigned int*)(unsigned)(uintptr_t)(const void*)l,
      16, 0, 0);
}

// 128x128 tile, K consumed 64/iter as two 32-panels (verified lane-linear
// global_load_lds layout, free 2-way bank pattern). kSteps64 = K/64.
__device__ __forceinline__ void gemm_core(const __bf16* __restrict__ pA,
                                          const __bf16* __restrict__ pB,
                                          int K, int kSteps64, int mb, int nb,
                                          floatx4 (&acc)[4][4]) {
  __shared__ __align__(16) __bf16 As0[BM * 32];
  __shared__ __align__(16) __bf16 As1[BM * 32];
  __shared__ __align__(16) __bf16 Bs0[BN * 32];
  __shared__ __align__(16) __bf16 Bs1[BN * 32];

  const int t = threadIdx.x;
  const int lane = t & 63;
  const int wave = t >> 6;
  const int quad = lane >> 4;
  const int l16 = lane & 15;
  const int wm = wave >> 1;
  const int wn = wave & 1;

  const __bf16* gA = pA + (long)(mb * BM + (t >> 2)) * K + ((t & 3) * 8);
  const __bf16* gB = pB + (long)(nb * BN + (t >> 2)) * K + ((t & 3) * 8);
  const long rowHalf = (long)64 * K;
  __bf16* lA0 = &As0[t * 8];
  __bf16* lA1 = &As1[t * 8];
  __bf16* lB0 = &Bs0[t * 8];
  __bf16* lB1 = &Bs1[t * 8];

  for (int kk = 0; kk < kSteps64; ++kk) {
    const long ko = (long)kk * 64;
    async_copy16(gA + ko, lA0);
    async_copy16(gA + ko + rowHalf, lA0 + 2048);
    async_copy16(gA + ko + 32, lA1);
    async_copy16(gA + ko + 32 + rowHalf, lA1 + 2048);
    async_copy16(gB + ko, lB0);
    async_copy16(gB + ko + rowHalf, lB0 + 2048);
    async_copy16(gB + ko + 32, lB1);
    async_copy16(gB + ko + 32 + rowHalf, lB1 + 2048);
    __syncthreads();

#pragma unroll
    for (int p = 0; p < 2; ++p) {
      const __bf16* As = p ? As1 : As0;
      const __bf16* Bs = p ? Bs1 : Bs0;
      bf16x8 af[4], bfr[4];
#pragma unroll
      for (int i = 0; i < 4; ++i) {
        af[i] = *(const bf16x8*)&As[(wm * 64 + i * 16 + l16) * 32 + quad * 8];
        bfr[i] = *(const bf16x8*)&Bs[(wn * 64 + i * 16 + l16) * 32 + quad * 8];
      }
#pragma unroll
      for (int i = 0; i < 4; ++i)
#pragma unroll
        for (int j = 0; j < 4; ++j)
          acc[i][j] = __builtin_amdgcn_mfma_f32_16x16x32_bf16(af[i], bfr[j],
                                                              acc[i][j], 0, 0, 0);
    }
    __syncthreads();
  }
}

// ---------------- fused QKV projection (z = 0:q, 1:k, 2:v-transposed) -------
// grid: 1536 flat. xcd=id&7 -> mb in {xcd*8..xcd*8+7} (A-slice L2-resident),
// inner order: mb fastest within an (nb,z) so B-panel reused 8x back-to-back.
__global__ void __launch_bounds__(256, 2)
gemm_qkv(const __bf16* __restrict__ xb, const __bf16* __restrict__ Wqkv,
         Bias3 bias, __bf16* __restrict__ qk, __bf16* __restrict__ Vt,
         int S, int D, int KD, int B) {
  const int id = blockIdx.x;
  const int xcd = id & 7;
  const int j = id >> 3;          // 192 per XCD
  const int mb = xcd * 8 + (j & 7);
  const int rest = j >> 3;        // 24
  const int nb = rest & 7;
  const int z = rest >> 3;

  floatx4 acc[4][4] = {};
  gemm_core(xb, Wqkv + (long)z * KD * D, D, D / 64, mb, nb, acc);

  const int t = threadIdx.x;
  const int lane = t & 63, wave = t >> 6;
  const int rb = (wave >> 1) * 64 + (lane >> 4) * 4;
  const int cb = (wave & 1) * 64 + (lane & 15);
  const float* bz = bias.b[z];

  if (z < 2) {
    __bf16* C = qk + (long)z * B * S * KD;
#pragma unroll
    for (int j4 = 0; j4 < 4; ++j4) {
      const int gc = nb * BN + cb + j4 * 16;
      const float bv = bz[gc];
#pragma unroll
      for (int i = 0; i < 4; ++i) {
        const int gr = mb * BM + rb + i * 16;
#pragma unroll
        for (int r = 0; r < 4; ++r)
          C[(long)(gr + r) * KD + gc] = (__bf16)(acc[i][j4][r] + bv);
      }
    }
  } else {
    // Vt[b][vd][s] = v[b][s][vd]; BM=128 rows lie in one batch (S%BM==0)
    const int bb = (mb * BM) / S;
    const int s0 = mb * BM - bb * S;
#pragma unroll
    for (int j4 = 0; j4 < 4; ++j4) {
      const int gc = nb * BN + cb + j4 * 16;  // vd
      const float bv = bz[gc];
#pragma unroll
      for (int i = 0; i < 4; ++i) {
        const int sr = s0 + rb + i * 16;
        bf16x4 o;
#pragma unroll
        for (int r = 0; r < 4; ++r) o[r] = (__bf16)(acc[i][j4][r] + bv);
        *(bf16x4*)&Vt[((long)bb * KD + gc) * S + sr] = o;
      }
    }
  }
}

// ---------------- scores: P = exp(|qk^T|/32) causal, + atomic rowsums -------
// grid: 1024 flat. Per XCD per batch: mb in {x, 15-x} (balanced: 17 active
// nb per pair). A-slice (8 q-panels, 2 MB) L2-resident per XCD.
__global__ void __launch_bounds__(256, 2)
gemm_scores(const __bf16* __restrict__ q, const __bf16* __restrict__ k,
            __bf16* __restrict__ P, float* __restrict__ lsum, int S, int KD) {
  const int id = blockIdx.x;
  const int xcd = id & 7;
  const int j = id >> 3;          // 128 per XCD
  const int nb = j & 15;
  const int comb = j >> 4;        // 8
  const int b = comb >> 1;
  const int mb = (comb & 1) ? (15 - xcd) : xcd;
  if (nb > mb) return;

  floatx4 acc[4][4] = {};
  gemm_core(q + (long)b * S * KD, k + (long)b * S * KD, KD, KD / 64, mb, nb, acc);

  const int t = threadIdx.x;
  const int lane = t & 63, wave = t >> 6;
  const int l16 = lane & 15;
  const int rb = (wave >> 1) * 64 + (lane >> 4) * 4;
  const int cb = (wave & 1) * 64 + l16;
  __bf16* C = P + (long)b * S * S;
  float* lrow = lsum + (long)b * S;
  const float sc = 0.03125f;  // 1/sqrt(1024)

#pragma unroll
  for (int i = 0; i < 4; ++i) {
#pragma unroll
    for (int r = 0; r < 4; ++r) {
      const int row = mb * BM + rb + i * 16 + r;
      float psum = 0.f;
#pragma unroll
      for (int j4 = 0; j4 < 4; ++j4) {
        const int col = nb * BN + cb + j4 * 16;
        const float p = (col <= row) ? __expf(fabsf(acc[i][j4][r] * sc)) : 0.f;
        psum += p;
        C[(long)row * S + col] = (__bf16)p;
      }
      psum += __shfl_xor(psum, 1, 64);
      psum += __shfl_xor(psum, 2, 64);
      psum += __shfl_xor(psum, 4, 64);
      psum += __shfl_xor(psum, 8, 64);
      if (l16 == 0) atomicAdd(&lrow[row], psum);
    }
  }
}

// ---------------- PV: O = (P @ V) / l, ragged causal k ----------------------
// grid: 512 flat. Same balanced mb in {x, 15-x} pairing (17 kSteps64/pair).
__global__ void __launch_bounds__(256, 2)
gemm_pv(const __bf16* __restrict__ P, const __bf16* __restrict__ Vt,
        const float* __restrict__ lsum, __bf16* __restrict__ O, int S, int VD) {
  const int id = blockIdx.x;
  const int xcd = id & 7;
  const int j = id >> 3;          // 64 per XCD
  const int nb = j & 7;
  const int comb = j >> 3;        // 8
  const int b = comb >> 1;
  const int mb = (comb & 1) ? (15 - xcd) : xcd;

  floatx4 acc[4][4] = {};
  gemm_core(P + (long)b * S * S, Vt + (long)b * VD * S, S, (mb + 1) * 2, mb, nb,
            acc);

  const int t = threadIdx.x;
  const int lane = t & 63, wave = t >> 6;
  const int rb = (wave >> 1) * 64 + (lane >> 4) * 4;
  const int cb = (wave & 1) * 64 + (lane & 15);
  const float* lrow = lsum + (long)b * S;

#pragma unroll
  for (int i = 0; i < 4; ++i) {
#pragma unroll
    for (int r = 0; r < 4; ++r) {
      const int row = mb * BM + rb + i * 16 + r;
      const float inv = 1.f / lrow[row];
#pragma unroll
      for (int j4 = 0; j4 < 4; ++j4) {
        const int col = nb * BN + cb + j4 * 16;
        O[((long)b * S + row) * VD + col] = (__bf16)(acc[i][j4][r] * inv);
      }
    }
  }
}

// ---------------- final projection: out = O @ Wo^T + bo (fp32) --------------
// grid: 512 flat. mb slice per XCD (A = O, 16 MB -> 2 MB/XCD resident).
__global__ void __launch_bounds__(256, 2)
gemm_out(const __bf16* __restrict__ O, const __bf16* __restrict__ Wob,
         const float* __restrict__ bo, float* __restrict__ out, int M, int N,
         int K) {
  const int id = blockIdx.x;
  const int xcd = id & 7;
  const int j = id >> 3;          // 64 per XCD
  const int mb = xcd * 8 + (j & 7);
  const int nb = j >> 3;          // 8

  floatx4 acc[4][4] = {};
  gemm_core(O, Wob, K, K / 64, mb, nb, acc);

  const int t = threadIdx.x;
  const int lane = t & 63, wave = t >> 6;
  const int rb = (wave >> 1) * 64 + (lane >> 4) * 4;
  const int cb = (wave & 1) * 64 + (lane & 15);

#pragma unroll
  for (int j4 = 0; j4 < 4; ++j4) {
    const int gc = nb * BN + cb + j4 * 16;
    const float bv = bo[gc];
#pragma unroll
    for (int i = 0; i < 4; ++i) {
      const int gr = mb * BM + rb + i * 16;
#pragma unroll
      for (int r = 0; r < 4; ++r) out[(long)(gr + r) * N + gc] = acc[i][j4][r] + bv;
    }
  }
}

// ---------------- prep: cast x, cast 4 weights, zero lsum (one dispatch) ----
__global__ void prep(const float* __restrict__ x, Ptr4 wp,
                     __bf16* __restrict__ xb, __bf16* __restrict__ Wb,
                     float* __restrict__ lsum) {
  const int bid = blockIdx.x;
  const int t = threadIdx.x;
  if (bid < 8192) {  // x: 8M elems = 2M float4 slots
    const long i = ((long)bid * 256 + t) * 4;
    const float4 f = *(const float4*)(x + i);
    bf16x4 o;
    o[0] = (__bf16)f.x; o[1] = (__bf16)f.y; o[2] = (__bf16)f.z; o[3] = (__bf16)f.w;
    *(bf16x4*)(xb + i) = o;
  } else if (bid < 12288) {  // weights: 4 x 1M elems
    const int slot = (bid - 8192) * 256 + t;
    const int which = slot >> 18;
    const long e = (long)(slot & 0x3ffff) * 4;
    const float4 f = *(const float4*)(wp.p[which] + e);
    bf16x4 o;
    o[0] = (__bf16)f.x; o[1] = (__bf16)f.y; o[2] = (__bf16)f.z; o[3] = (__bf16)f.w;
    *(bf16x4*)(Wb + ((long)which << 20) + e) = o;
  } else {  // zero lsum: 8192 floats
#pragma unroll
    for (int e = 0; e < 8; ++e)
      *(float4*)(lsum + (e * 256 + t) * 4) = float4{0.f, 0.f, 0.f, 0.f};
  }
}

extern "C" void kernel_launch(void* const* d_in, const int* in_sizes, int n_in,
                              void* d_out, int out_size, void* d_ws, size_t ws_size,
                              hipStream_t stream) {
  const float* x = (const float*)d_in[0];
  const float* Wq = (const float*)d_in[1];
  const float* bq = (const float*)d_in[2];
  const float* Wk = (const float*)d_in[3];
  const float* bk = (const float*)d_in[4];
  const float* Wv = (const float*)d_in[5];
  const float* bv = (const float*)d_in[6];
  const float* Wo = (const float*)d_in[7];
  const float* bo = (const float*)d_in[8];
  float* out = (float*)d_out;

  constexpr int B = 4, S = 2048, D = 1024, KD = 1024, VD = 1024;
  constexpr long MB_ = 1024 * 1024;

  char* w = (char*)d_ws;
  __bf16* xb = (__bf16*)(w);              // 16 MB (reused as O later)
  __bf16* qk = (__bf16*)(w + 16 * MB_);   // 32 MB: q then k
  __bf16* Vt = (__bf16*)(w + 48 * MB_);   // 16 MB
  __bf16* P  = (__bf16*)(w + 64 * MB_);   // 32 MB
  __bf16* Wb = (__bf16*)(w + 96 * MB_);   // 8 MB: Wq,Wk,Wv,Wo bf16 contiguous
  float* lsum = (float*)(w + 104 * MB_);  // 32 KB
  __bf16* O = xb;  // xb dead after qkv

  Ptr4 wp{{Wq, Wk, Wv, Wo}};
  prep<<<12289, 256, 0, stream>>>(x, wp, xb, Wb, lsum);

  Bias3 b3{{bq, bk, bv}};
  gemm_qkv<<<1536, 256, 0, stream>>>(xb, Wb, b3, qk, Vt, S, D, KD, B);

  gemm_scores<<<1024, 256, 0, stream>>>(qk, qk + (long)B * S * KD, P, lsum, S, KD);

  gemm_pv<<<512, 256, 0, stream>>>(P, Vt, lsum, O, S, VD);

  gemm_out<<<512, 256, 0, stream>>>(O, Wb + 3l * D * VD, bo, out, B * S, D, VD);
}

// Round 5
// 261.004 us; speedup vs baseline: 1.3096x; 1.0132x over previous
//
#include <hip/hip_runtime.h>
#include <hip/hip_bf16.h>
#include <cstdint>

// ---------------------------------------------------------------------------
// SingleHeadAttentionLayer: B=4, S=2048, D=KD=VD=1024, fp32 in/out.
// Round 5: algebraic elimination of the output projection.
//   out = (P/l)*v*Wo^T + bo = (P/l)*(x*(Wo*Wv)^T + bv*Wo^T) + bo
// Pipeline:
//   prep: cast x; cast Wq,Wk,Wo; transpose-cast Wv; bvo = bv*Wo^T; zero lsum
//   Wvo = Wo*Wv                       (64-block GEMM, 2.1 GF)
//   q,k,Ut = x@{Wq,Wk,Wvo}^T + bias   (one dispatch, z=3; U written transposed)
//   P = exp(|q k^T|/32) causal, rowsums via in-epilogue atomics
//   out = (P @ U)/l + bo              (ragged causal k, fp32)
// XCD-locality swizzle (verified round 4: FETCH 186->41 MB) kept throughout.
// ---------------------------------------------------------------------------

#define BM 128
#define BN 128

typedef __attribute__((ext_vector_type(8))) __bf16 bf16x8;
typedef __attribute__((ext_vector_type(4))) __bf16 bf16x4;
typedef __attribute__((ext_vector_type(4))) float floatx4;

struct WPtr3 { const __bf16* w[3]; };
struct BPtr3 { const float* b[3]; };
struct Ptr3 { const float* p[3]; };

__device__ __forceinline__ void async_copy16(const __bf16* g, const __bf16* l) {
  __builtin_amdgcn_global_load_lds(
      (const __attribute__((address_space(1))) unsigned int*)(const void*)g,
      (__attribute__((address_space(3))) unsigned int*)(unsigned)(uintptr_t)(const void*)l,
      16, 0, 0);
}

// 128x128 tile, K consumed 64/iter as two 32-panels (verified lane-linear
// global_load_lds layout, free 2-way bank pattern). kSteps64 = K/64.
__device__ __forceinline__ void gemm_core(const __bf16* __restrict__ pA,
                                          const __bf16* __restrict__ pB,
                                          int K, int kSteps64, int mb, int nb,
                                          floatx4 (&acc)[4][4]) {
  __shared__ __align__(16) __bf16 As0[BM * 32];
  __shared__ __align__(16) __bf16 As1[BM * 32];
  __shared__ __align__(16) __bf16 Bs0[BN * 32];
  __shared__ __align__(16) __bf16 Bs1[BN * 32];

  const int t = threadIdx.x;
  const int lane = t & 63;
  const int wave = t >> 6;
  const int quad = lane >> 4;
  const int l16 = lane & 15;
  const int wm = wave >> 1;
  const int wn = wave & 1;

  const __bf16* gA = pA + (long)(mb * BM + (t >> 2)) * K + ((t & 3) * 8);
  const __bf16* gB = pB + (long)(nb * BN + (t >> 2)) * K + ((t & 3) * 8);
  const long rowHalf = (long)64 * K;
  __bf16* lA0 = &As0[t * 8];
  __bf16* lA1 = &As1[t * 8];
  __bf16* lB0 = &Bs0[t * 8];
  __bf16* lB1 = &Bs1[t * 8];

  for (int kk = 0; kk < kSteps64; ++kk) {
    const long ko = (long)kk * 64;
    async_copy16(gA + ko, lA0);
    async_copy16(gA + ko + rowHalf, lA0 + 2048);
    async_copy16(gA + ko + 32, lA1);
    async_copy16(gA + ko + 32 + rowHalf, lA1 + 2048);
    async_copy16(gB + ko, lB0);
    async_copy16(gB + ko + rowHalf, lB0 + 2048);
    async_copy16(gB + ko + 32, lB1);
    async_copy16(gB + ko + 32 + rowHalf, lB1 + 2048);
    __syncthreads();

#pragma unroll
    for (int p = 0; p < 2; ++p) {
      const __bf16* As = p ? As1 : As0;
      const __bf16* Bs = p ? Bs1 : Bs0;
      bf16x8 af[4], bfr[4];
#pragma unroll
      for (int i = 0; i < 4; ++i) {
        af[i] = *(const bf16x8*)&As[(wm * 64 + i * 16 + l16) * 32 + quad * 8];
        bfr[i] = *(const bf16x8*)&Bs[(wn * 64 + i * 16 + l16) * 32 + quad * 8];
      }
#pragma unroll
      for (int i = 0; i < 4; ++i)
#pragma unroll
        for (int j = 0; j < 4; ++j)
          acc[i][j] = __builtin_amdgcn_mfma_f32_16x16x32_bf16(af[i], bfr[j],
                                                              acc[i][j], 0, 0, 0);
    }
    __syncthreads();
  }
}

// ---------------- Wvo = Wo @ Wv  (A=Wob [D][VD], B=Wvt [D][VD]) ------------
__global__ void __launch_bounds__(256, 2)
gemm_wvo(const __bf16* __restrict__ Wob, const __bf16* __restrict__ Wvt,
         __bf16* __restrict__ Wvo) {
  const int id = blockIdx.x;  // 64 blocks: 8x8
  const int mb = id >> 3, nb = id & 7;
  floatx4 acc[4][4] = {};
  gemm_core(Wob, Wvt, 1024, 16, mb, nb, acc);

  const int t = threadIdx.x;
  const int lane = t & 63, wave = t >> 6;
  const int rb = (wave >> 1) * 64 + (lane >> 4) * 4;
  const int cb = (wave & 1) * 64 + (lane & 15);
#pragma unroll
  for (int j4 = 0; j4 < 4; ++j4) {
    const int gc = nb * BN + cb + j4 * 16;
#pragma unroll
    for (int i = 0; i < 4; ++i) {
      const int gr = mb * BM + rb + i * 16;
#pragma unroll
      for (int r = 0; r < 4; ++r)
        Wvo[(long)(gr + r) * 1024 + gc] = (__bf16)acc[i][j4][r];
    }
  }
}

// ---------------- fused QKU projection (z = 0:q, 1:k, 2:U-transposed) -------
// grid: 1536 flat; xcd=id&7 -> mb slice L2-resident per XCD (round-4 verified)
__global__ void __launch_bounds__(256, 2)
gemm_qku(const __bf16* __restrict__ xb, WPtr3 wgt, BPtr3 bias,
         __bf16* __restrict__ qk, __bf16* __restrict__ Ut,
         int S, int D, int KD, int B) {
  const int id = blockIdx.x;
  const int xcd = id & 7;
  const int j = id >> 3;          // 192 per XCD
  const int mb = xcd * 8 + (j & 7);
  const int rest = j >> 3;        // 24
  const int nb = rest & 7;
  const int z = rest >> 3;

  floatx4 acc[4][4] = {};
  gemm_core(xb, wgt.w[z], D, D / 64, mb, nb, acc);

  const int t = threadIdx.x;
  const int lane = t & 63, wave = t >> 6;
  const int rb = (wave >> 1) * 64 + (lane >> 4) * 4;
  const int cb = (wave & 1) * 64 + (lane & 15);
  const float* bz = bias.b[z];

  if (z < 2) {
    __bf16* C = qk + (long)z * B * S * KD;
#pragma unroll
    for (int j4 = 0; j4 < 4; ++j4) {
      const int gc = nb * BN + cb + j4 * 16;
      const float bv = bz[gc];
#pragma unroll
      for (int i = 0; i < 4; ++i) {
        const int gr = mb * BM + rb + i * 16;
#pragma unroll
        for (int r = 0; r < 4; ++r)
          C[(long)(gr + r) * KD + gc] = (__bf16)(acc[i][j4][r] + bv);
      }
    }
  } else {
    // Ut[b][dout][s] = U[b][s][dout]; BM=128 rows lie in one batch (S%BM==0)
    const int bb = (mb * BM) / S;
    const int s0 = mb * BM - bb * S;
#pragma unroll
    for (int j4 = 0; j4 < 4; ++j4) {
      const int gc = nb * BN + cb + j4 * 16;  // dout
      const float bv = bz[gc];
#pragma unroll
      for (int i = 0; i < 4; ++i) {
        const int sr = s0 + rb + i * 16;
        bf16x4 o;
#pragma unroll
        for (int r = 0; r < 4; ++r) o[r] = (__bf16)(acc[i][j4][r] + bv);
        *(bf16x4*)&Ut[((long)bb * D + gc) * S + sr] = o;
      }
    }
  }
}

// ---------------- scores: P = exp(|qk^T|/32) causal, + atomic rowsums -------
// grid: 1024 flat; balanced mb in {x,15-x} per XCD per batch.
__global__ void __launch_bounds__(256, 2)
gemm_scores(const __bf16* __restrict__ q, const __bf16* __restrict__ k,
            __bf16* __restrict__ P, float* __restrict__ lsum, int S, int KD) {
  const int id = blockIdx.x;
  const int xcd = id & 7;
  const int j = id >> 3;          // 128 per XCD
  const int nb = j & 15;
  const int comb = j >> 4;        // 8
  const int b = comb >> 1;
  const int mb = (comb & 1) ? (15 - xcd) : xcd;
  if (nb > mb) return;

  floatx4 acc[4][4] = {};
  gemm_core(q + (long)b * S * KD, k + (long)b * S * KD, KD, KD / 64, mb, nb, acc);

  const int t = threadIdx.x;
  const int lane = t & 63, wave = t >> 6;
  const int l16 = lane & 15;
  const int rb = (wave >> 1) * 64 + (lane >> 4) * 4;
  const int cb = (wave & 1) * 64 + l16;
  __bf16* C = P + (long)b * S * S;
  float* lrow = lsum + (long)b * S;
  const float sc = 0.03125f;  // 1/sqrt(1024)

#pragma unroll
  for (int i = 0; i < 4; ++i) {
#pragma unroll
    for (int r = 0; r < 4; ++r) {
      const int row = mb * BM + rb + i * 16 + r;
      float psum = 0.f;
#pragma unroll
      for (int j4 = 0; j4 < 4; ++j4) {
        const int col = nb * BN + cb + j4 * 16;
        const float p = (col <= row) ? __expf(fabsf(acc[i][j4][r] * sc)) : 0.f;
        psum += p;
        C[(long)row * S + col] = (__bf16)p;
      }
      psum += __shfl_xor(psum, 1, 64);
      psum += __shfl_xor(psum, 2, 64);
      psum += __shfl_xor(psum, 4, 64);
      psum += __shfl_xor(psum, 8, 64);
      if (l16 == 0) atomicAdd(&lrow[row], psum);
    }
  }
}

// ---------------- final: out = (P @ U)/l + bo, fp32, ragged causal k --------
// grid: 512 flat; balanced mb in {x,15-x} pairing (17 kSteps64 per pair).
__global__ void __launch_bounds__(256, 2)
gemm_pvo(const __bf16* __restrict__ P, const __bf16* __restrict__ Ut,
         const float* __restrict__ lsum, const float* __restrict__ bo,
         float* __restrict__ out, int S, int D) {
  const int id = blockIdx.x;
  const int xcd = id & 7;
  const int j = id >> 3;          // 64 per XCD
  const int nb = j & 7;
  const int comb = j >> 3;        // 8
  const int b = comb >> 1;
  const int mb = (comb & 1) ? (15 - xcd) : xcd;

  floatx4 acc[4][4] = {};
  gemm_core(P + (long)b * S * S, Ut + (long)b * D * S, S, (mb + 1) * 2, mb, nb,
            acc);

  const int t = threadIdx.x;
  const int lane = t & 63, wave = t >> 6;
  const int rb = (wave >> 1) * 64 + (lane >> 4) * 4;
  const int cb = (wave & 1) * 64 + (lane & 15);
  const float* lrow = lsum + (long)b * S;

#pragma unroll
  for (int i = 0; i < 4; ++i) {
#pragma unroll
    for (int r = 0; r < 4; ++r) {
      const int row = mb * BM + rb + i * 16 + r;
      const float inv = 1.f / lrow[row];
#pragma unroll
      for (int j4 = 0; j4 < 4; ++j4) {
        const int col = nb * BN + cb + j4 * 16;
        out[((long)b * S + row) * D + col] = acc[i][j4][r] * inv + bo[col];
      }
    }
  }
}

// ---------------- prep --------------------------------------------------
// [0,8192): cast x | [8192,11264): cast Wq,Wk,Wo | [11264,11520): Wv^T cast
// [11520,12544): bvo[d] = sum_v bv[v]*Wo[d][v] | 12544: zero lsum
__global__ void prep(const float* __restrict__ x, Ptr3 wp,
                     const float* __restrict__ Wv, const float* __restrict__ bv,
                     __bf16* __restrict__ xb, __bf16* __restrict__ Wb,
                     __bf16* __restrict__ Wvt, float* __restrict__ bvo,
                     float* __restrict__ lsum) {
  __shared__ __bf16 tile[64][66];
  __shared__ float wsum[4];
  const int bid = blockIdx.x;
  const int t = threadIdx.x;
  if (bid < 8192) {  // x: 8M elems
    const long i = ((long)bid * 256 + t) * 4;
    const float4 f = *(const float4*)(x + i);
    bf16x4 o;
    o[0] = (__bf16)f.x; o[1] = (__bf16)f.y; o[2] = (__bf16)f.z; o[3] = (__bf16)f.w;
    *(bf16x4*)(xb + i) = o;
  } else if (bid < 11264) {  // Wq, Wk, Wo: 3 x 1M elems
    const int slot = (bid - 8192) * 256 + t;
    const int which = slot >> 18;
    const long e = (long)(slot & 0x3ffff) * 4;
    const float4 f = *(const float4*)(wp.p[which] + e);
    bf16x4 o;
    o[0] = (__bf16)f.x; o[1] = (__bf16)f.y; o[2] = (__bf16)f.z; o[3] = (__bf16)f.w;
    *(bf16x4*)(Wb + ((long)which << 20) + e) = o;
  } else if (bid < 11520) {  // Wvt[din][v] = Wv[v][din], 256 64x64 tiles
    const int idx = bid - 11264;
    const int r0 = (idx >> 4) * 64, c0 = (idx & 15) * 64;
#pragma unroll
    for (int e = 0; e < 16; ++e) {
      const int i = e * 256 + t;
      const int r = i >> 6, c = i & 63;
      tile[r][c] = (__bf16)Wv[(long)(r0 + r) * 1024 + (c0 + c)];
    }
    __syncthreads();
#pragma unroll
    for (int e = 0; e < 16; ++e) {
      const int i = e * 256 + t;
      const int r = i >> 6, c = i & 63;
      Wvt[(long)(c0 + r) * 1024 + (r0 + c)] = tile[c][r];
    }
  } else if (bid < 12544) {  // bvo
    const int d = bid - 11520;
    const float* row = wp.p[2] + (long)d * 1024;  // Wo row d
    float s = 0.f;
    for (int v = t; v < 1024; v += 256) s += bv[v] * row[v];
#pragma unroll
    for (int off = 32; off > 0; off >>= 1) s += __shfl_down(s, off, 64);
    if ((t & 63) == 0) wsum[t >> 6] = s;
    __syncthreads();
    if (t == 0) bvo[d] = wsum[0] + wsum[1] + wsum[2] + wsum[3];
  } else {  // zero lsum: 8192 floats
#pragma unroll
    for (int e = 0; e < 8; ++e)
      *(float4*)(lsum + (e * 256 + t) * 4) = float4{0.f, 0.f, 0.f, 0.f};
  }
}

extern "C" void kernel_launch(void* const* d_in, const int* in_sizes, int n_in,
                              void* d_out, int out_size, void* d_ws, size_t ws_size,
                              hipStream_t stream) {
  const float* x = (const float*)d_in[0];
  const float* Wq = (const float*)d_in[1];
  const float* bq = (const float*)d_in[2];
  const float* Wk = (const float*)d_in[3];
  const float* bk = (const float*)d_in[4];
  const float* Wv = (const float*)d_in[5];
  const float* bv = (const float*)d_in[6];
  const float* Wo = (const float*)d_in[7];
  const float* bo = (const float*)d_in[8];
  float* out = (float*)d_out;

  constexpr int B = 4, S = 2048, D = 1024, KD = 1024;
  constexpr long MB_ = 1024 * 1024;

  char* w = (char*)d_ws;
  __bf16* xb = (__bf16*)(w);               // 16 MB
  __bf16* qk = (__bf16*)(w + 16 * MB_);    // 32 MB: q then k
  __bf16* Ut = (__bf16*)(w + 48 * MB_);    // 16 MB
  __bf16* P  = (__bf16*)(w + 64 * MB_);    // 32 MB
  __bf16* Wb = (__bf16*)(w + 96 * MB_);    // 6 MB: Wqb, Wkb, Wob
  __bf16* Wvt = (__bf16*)(w + 102 * MB_);  // 2 MB
  __bf16* Wvo = (__bf16*)(w + 104 * MB_);  // 2 MB
  float* lsum = (float*)(w + 106 * MB_);   // 32 KB
  float* bvo = (float*)(w + 106 * MB_ + 65536);  // 4 KB

  __bf16* Wqb = Wb;
  __bf16* Wkb = Wb + (1l << 20);
  __bf16* Wob = Wb + (2l << 20);

  Ptr3 wp{{Wq, Wk, Wo}};
  prep<<<12545, 256, 0, stream>>>(x, wp, Wv, bv, xb, Wb, Wvt, bvo, lsum);

  gemm_wvo<<<64, 256, 0, stream>>>(Wob, Wvt, Wvo);

  WPtr3 w3{{Wqb, Wkb, Wvo}};
  BPtr3 b3{{bq, bk, bvo}};
  gemm_qku<<<1536, 256, 0, stream>>>(xb, w3, b3, qk, Ut, S, D, KD, B);

  gemm_scores<<<1024, 256, 0, stream>>>(qk, qk + (long)B * S * KD, P, lsum, S, KD);

  gemm_pvo<<<512, 256, 0, stream>>>(P, Ut, lsum, bo, out, S, D);
}